// Round 12
// baseline (226.497 us; speedup 1.0000x reference)
//
#include <hip/hip_runtime.h>
#include <hip/hip_bf16.h>

typedef unsigned short u16;
typedef unsigned int u32;
typedef __attribute__((ext_vector_type(4))) float f32x4;
typedef __attribute__((ext_vector_type(8))) short s16x8;
typedef __attribute__((ext_vector_type(4))) short s16x4;

#define DEV static __device__ __forceinline__

DEV u16 f2bf(float f){ return __builtin_bit_cast(u16, __float2bfloat16(f)); }
DEV float bf2f(u16 v){ union{u32 u;float f;}x; x.u = ((u32)v)<<16; return x.f; }
DEV float bitsf(u32 u){ union{u32 u;float f;}x; x.u = u; return x.f; }

DEV f32x4 MF(s16x8 a, s16x8 b, f32x4 c){ return __builtin_amdgcn_mfma_f32_16x16x32_bf16(a,b,c,0,0,0); }

DEV s16x8 frag64(const u16* lds, int row, int slot){
  return *(const s16x8*)(lds + row*64 + ((slot ^ (row&7))<<3));
}

// ---------------- prep: W[k][n] f32 -> WT[n][k] bf16, 5 matrices ----------------
__global__ __launch_bounds__(256) void k_prep(
  const float* __restrict__ Wq, const float* __restrict__ Wk, const float* __restrict__ Wv,
  const float* __restrict__ Wp, const float* __restrict__ Wo, u16* __restrict__ WT)
{
  const int bx = blockIdx.x; const int mat = bx>>6, tile = bx&63;
  const float* W = (mat==0)?Wq:(mat==1)?Wk:(mat==2)?Wv:(mat==3)?Wp:Wo;
  u16* dst = WT + mat*262144;
  const int k0 = (tile>>3)<<6, n0 = (tile&7)<<6;
  __shared__ u16 L[64*68];
  const int t = threadIdx.x;
#pragma unroll
  for (int i=0;i<4;i++){
    int id = t + 256*i; int row = id>>4, c4 = (id&15)<<2;
    float4 v = *(const float4*)(W + (k0+row)*512 + n0 + c4);
    s16x4 o; o[0]=(short)f2bf(v.x); o[1]=(short)f2bf(v.y); o[2]=(short)f2bf(v.z); o[3]=(short)f2bf(v.w);
    *(s16x4*)(L + row*68 + c4) = o;
  }
  __syncthreads();
#pragma unroll
  for (int i=0;i<2;i++){
    int id = t + 256*i; int nl = id>>3, slot = id&7;
    s16x8 v;
#pragma unroll
    for (int j=0;j<8;j++) v[j] = (short)L[(slot*8+j)*68 + nl];
    *(s16x8*)(dst + (n0+nl)*512 + k0 + slot*8) = v;
  }
}

// ---------------- projections (1D grid, XCD-chunked) ----------------
__global__ __launch_bounds__(256,2) void k_proj(
  const float* __restrict__ Xq, const float* __restrict__ Xk,
  const float* __restrict__ Xv, const float* __restrict__ Xp,
  const u16* __restrict__ WT,
  const float* __restrict__ bq, const float* __restrict__ bk, const float* __restrict__ bv,
  const float* __restrict__ ub, const float* __restrict__ vb,
  u16* __restrict__ Qu, u16* __restrict__ Qv, u16* __restrict__ Kb,
  u16* __restrict__ Pb, u16* __restrict__ Vt)
{
  const int Lb = blockIdx.x;
  const int xcd = Lb & 7, li = Lb >> 3;        // li 0..127
  const int n0  = (li & 3) * 128;
  const int job = (li >> 2) & 3;
  const int m0  = (xcd*8 + (li >> 4)) * 128;
  const float* X = (job==0)?Xq:(job==1)?Xk:(job==2)?Xp:Xv;
  const int wsel = (job==0)?0:(job==1)?1:(job==2)?3:2;
  const u16* W = WT + wsel*262144;
  __shared__ u16 As[128*64];
  __shared__ u16 Bs[128*64];
  const int t = threadIdx.x, lane = t&63, w = t>>6;
  const int wm = w&1, wn = w>>1;
  f32x4 acc[4][4];
#pragma unroll
  for (int i=0;i<4;i++)
#pragma unroll
    for (int j=0;j<4;j++) acc[i][j] = (f32x4){0.f,0.f,0.f,0.f};

  for (int kt=0; kt<8; ++kt){
    const int k0 = kt*64;
    __syncthreads();
#pragma unroll
    for (int i=0;i<8;i++){
      int id = t + 256*i; int row = id>>4; int c4 = (id&15)<<2;
      float4 v = *(const float4*)(X + (m0+row)*512 + k0 + c4);
      s16x4 o; o[0]=(short)f2bf(v.x); o[1]=(short)f2bf(v.y); o[2]=(short)f2bf(v.z); o[3]=(short)f2bf(v.w);
      *(s16x4*)(As + row*64 + ((((c4>>3)^(row&7))<<3) + (c4&4))) = o;
    }
#pragma unroll
    for (int i=0;i<4;i++){
      int id = t + 256*i; int row = id>>3, slot = id&7;
      s16x8 v = *(const s16x8*)(W + (n0+row)*512 + k0 + slot*8);
      *(s16x8*)(Bs + row*64 + ((slot^(row&7))<<3)) = v;
    }
    __syncthreads();
#pragma unroll
    for (int kk=0;kk<2;kk++){
      const int slotk = kk*4 + (lane>>4);
      s16x8 xf[4], wf[4];
#pragma unroll
      for (int j=0;j<4;j++){ int r = wm*64 + j*16 + (lane&15); xf[j] = frag64(As, r, slotk); }
#pragma unroll
      for (int i=0;i<4;i++){ int r = wn*64 + i*16 + (lane&15); wf[i] = frag64(Bs, r, slotk); }
      if (job != 3){
#pragma unroll
        for (int i=0;i<4;i++)
#pragma unroll
          for (int j=0;j<4;j++) acc[i][j] = MF(wf[i], xf[j], acc[i][j]);   // D[n][m]
      } else {
#pragma unroll
        for (int i=0;i<4;i++)
#pragma unroll
          for (int j=0;j<4;j++) acc[i][j] = MF(xf[i], wf[j], acc[i][j]);   // D[m][n]
      }
    }
  }

  const int b = m0>>10;
  if (job != 3){
#pragma unroll
    for (int i=0;i<4;i++){
      const int n = n0 + wn*64 + i*16 + ((lane>>4)<<2);
      const int hh = n>>6, d = n&63;
      f32x4 b1 = {0.f,0.f,0.f,0.f}, b2 = {0.f,0.f,0.f,0.f};
      if (job==0){
        f32x4 q4 = *(const f32x4*)(bq+n); f32x4 u4 = *(const f32x4*)(ub+n); f32x4 v4 = *(const f32x4*)(vb+n);
        b1 = q4 + u4; b2 = q4 + v4;
      } else if (job==1){
        b1 = *(const f32x4*)(bk+n);
      }
#pragma unroll
      for (int j=0;j<4;j++){
        const int m = m0 + wm*64 + j*16 + (lane&15);
        const int s = m&1023;
        const int off = ((b*8+hh)*1024 + s)*64 + d;
        f32x4 a = acc[i][j];
        s16x4 o1;
#pragma unroll
        for (int r=0;r<4;r++) o1[r] = (short)f2bf(a[r]+b1[r]);
        if (job==0){
          *(s16x4*)(Qu+off) = o1;
          s16x4 o2;
#pragma unroll
          for (int r=0;r<4;r++) o2[r] = (short)f2bf(a[r]+b2[r]);
          *(s16x4*)(Qv+off) = o2;
        } else if (job==1) *(s16x4*)(Kb+off) = o1;
        else               *(s16x4*)(Pb+off) = o1;
      }
    }
  } else {
#pragma unroll
    for (int j=0;j<4;j++){
      const int n = n0 + wn*64 + j*16 + (lane&15);
      const int hh = n>>6, d = n&63;
      const float bvn = bv[n];
#pragma unroll
      for (int i=0;i<4;i++){
        const int m = m0 + wm*64 + i*16 + ((lane>>4)<<2);
        const int s = m&1023;
        f32x4 a = acc[i][j];
        s16x4 o;
#pragma unroll
        for (int r=0;r<4;r++) o[r] = (short)f2bf(a[r]+bvn);
        *(s16x4*)(Vt + ((b*8+hh)*64 + d)*1024 + s) = o;
      }
    }
  }
}

// ---------------- fused rel-shift attention: barrier-free k-loops ----------------
// Each wave stages ONLY the 16 tile rows it reads into a private 2KB LDS slice
// -> zero cross-wave sharing in the k-loops -> 5 barriers total.
// sc = 32 rows: PS row 0 tail (jj>=1023-q0) and PS row 32 head (jj<=990-q0)
// share physical row 0 (disjoint ranges, both unswizzled). pmax/stats overlay
// into wave slices (wave-local writes; barrier-separated reads).
#define SC_SLOT(q, slot) ((((slot)) & ~7) | ((((slot))&7) ^ ((q)&7)))

__global__ __launch_bounds__(512,2) void k_attn(
  const u16* __restrict__ Qu, const u16* __restrict__ Qv,
  const u16* __restrict__ Kb, const u16* __restrict__ Pb,
  const u16* __restrict__ Vt, u16* __restrict__ Ctx)
{
  const int Lb = blockIdx.x;
  const int xcd = Lb & 7, li = Lb >> 3;       // 8 bh per XCD -> L2-resident K/P/V
  const int bh = xcd*8 + (li>>5);
  const int qb = li & 31;
  const int q0 = qb*32;
  const u16* Qu_ = Qu + bh*65536;
  const u16* Qv_ = Qv + bh*65536;
  const u16* Kb_ = Kb + bh*65536;
  const u16* Pb_ = Pb + bh*65536;
  const u16* Vt_ = Vt + bh*65536;
  u16* Ctx_ = Ctx + bh*65536;
  __shared__ u16 sc[32*1024];                 // 65536 B
  __shared__ u16 Ts[8*1024];                  // 16384 B: 8 private wave slices
  const int t = threadIdx.x, lane = t&63, w = t>>6;
  const int l15 = lane&15, lg = lane>>4;
  const int qband = w&1, sub = w>>1;
  const int qi = qband*16 + l15;
  const int q  = q0 + qi;
  u16* myTs = Ts + w*1024;
  float* myTsF = (float*)myTs;

  // per-lane slice staging coords: 2 chunks (row srowL, slots ssl0, ssl0+1)
  const int srowL = lane>>2;                  // 0..15
  const int ssl0  = (lane&3)<<1;              // 0,2,4,6
  u16* tw0 = myTs + srowL*64 + (((ssl0  )^(srowL&7))<<3);
  u16* tw1 = myTs + srowL*64 + (((ssl0+1)^(srowL&7))<<3);
  const int priBand = w>>2, jtp = w&3;
  const u16* gP = Pb_ + (jtp*16 + srowL)*64 + ssl0*8;
  const u16* gK = Kb_ + (sub*16 + srowL)*64 + ssl0*8;
  const u16* gV = Vt_ + (sub*16 + srowL)*1024 + ssl0*8;

  // ---- P tile 0/1 prefetch (latency hides under Qv preloads)
  s16x8 pa0 = *(const s16x8*)(gP);
  s16x8 pa1 = *(const s16x8*)(gP + 8);
  s16x8 pb0 = *(const s16x8*)(gP + 4096);
  s16x8 pb1 = *(const s16x8*)(gP + 4096 + 8);

  // ---- preload Qv fragments: primary band, overlap band rows 17..32
  s16x8 qvp[2], qvb2[2];
#pragma unroll
  for (int kk=0;kk<2;kk++){
    qvp[kk]  = *(const s16x8*)(Qv_ + (q0 + priBand*16 + l15)*64 + (kk*4+lg)*8);
    int r2 = q0 + 17 + l15; if (r2 > 1023) r2 = 1023;   // q0=992 edge: row32 unused
    qvb2[kk] = *(const s16x8*)(Qv_ + r2*64 + (kk*4+lg)*8);
  }

  // ---- phase 1: raw PS rows -> sc (swzA); NO barriers (private slices)
  {
#pragma unroll
    for (int u=0; u<16; ++u){
      *(s16x8*)tw0 = pa0;
      *(s16x8*)tw1 = pa1;
      pa0 = pb0; pa1 = pb1;
      if (u+2<16){
        pb0 = *(const s16x8*)(gP + (u+2)*4096);
        pb1 = *(const s16x8*)(gP + (u+2)*4096 + 8);
      }
      {
        f32x4 ps = {0.f,0.f,0.f,0.f};
#pragma unroll
        for (int kk=0;kk<2;kk++){
          s16x8 pf = frag64(myTs, l15, kk*4+lg);
          ps = MF(pf, qvp[kk], ps);           // PS[q=priBand*16+l15][j=jtp*16+lg*4+r]
        }
        const int prow = priBand*16 + l15;
        const int j0 = u*64 + jtp*16 + lg*4;
        if (prow){
          s16x4 o;
#pragma unroll
          for (int r=0;r<4;r++) o[r] = (short)f2bf(ps[r]);
          *(s16x4*)(sc + prow*1024 + ((((j0>>2) ^ ((prow&15)<<1)))<<2)) = o;
        } else {
          // row 0: only the tail jj >= 1023-q0 is ever read; head belongs to PS row 32
#pragma unroll
          for (int r=0;r<4;r++){
            const int jj = j0 + r;
            if (jj >= 1023 - q0) sc[jj] = f2bf(ps[r]);  // row0 unswizzled
          }
        }
      }
      if ((u&1) == (w>>2)){                   // overlap band rows 17..32, keep row 32
        f32x4 ps = {0.f,0.f,0.f,0.f};
#pragma unroll
        for (int kk=0;kk<2;kk++){
          s16x8 pf = frag64(myTs, l15, kk*4+lg);
          ps = MF(pf, qvb2[kk], ps);
        }
        if (l15 == 15){
          const int j0 = u*64 + (w&3)*16 + lg*4;
#pragma unroll
          for (int r=0;r<4;r++){
            const int jj = j0 + r;
            if (jj <= 990 - q0) sc[jj] = f2bf(ps[r]);   // phys row 0 head, unswizzled
          }
        }
      }
    }
  }

  __syncthreads();                            // B1: PS complete -> gather may read

  // ---- hoisted: Qu fragments + K tile 0/1 prefetch (hide under gather VALU)
  s16x8 qfu[2];
#pragma unroll
  for (int kk=0;kk<2;kk++)
    qfu[kk] = *(const s16x8*)(Qu_ + q*64 + (kk*4+lg)*8);
  s16x8 ka0 = *(const s16x8*)(gK);
  s16x8 ka1 = *(const s16x8*)(gK + 8);
  s16x8 kb0 = *(const s16x8*)(gK + 4096);
  s16x8 kb1 = *(const s16x8*)(gK + 4096 + 8);

  // ---- gather pre-pass: rel-shifted pos for this thread's 64 phase-2 cells
  u32 stash[32];
#pragma unroll
  for (int kt=0; kt<16; ++kt){
#pragma unroll
    for (int rp=0; rp<2; ++rp){
      u32 wv = 0;
#pragma unroll
      for (int hh=0; hh<2; ++hh){
        const int k = kt*64 + sub*16 + lg*4 + rp*2 + hh;
        const int above = (k > q) ? 1 : 0;
        int jj = above ? (k - q - 2) : (1023 - q + k);
        const bool zero = (k == q+1);
        if (jj < 0) jj = 0;
        const int phys = (qi + above) & 31;
        const int addr = phys*1024 + ((((jj>>2) ^ ((phys&15)<<1)))<<2) + (jj&3);
        u32 v = zero ? 0u : (u32)sc[addr];
        wv |= v << (16*hh);
      }
      stash[kt*2+rp] = wv;
    }
  }

  __syncthreads();                            // B2: gather done -> sc may be overwritten

  // ---- phase 2: content Qu.K^T + stash -> sc (swzB); NO barriers
  float rmax = -1e30f;
  {
#pragma unroll
    for (int kt=0; kt<16; ++kt){
      *(s16x8*)tw0 = ka0;
      *(s16x8*)tw1 = ka1;
      ka0 = kb0; ka1 = kb1;
      if (kt+2<16){
        kb0 = *(const s16x8*)(gK + (kt+2)*4096);
        kb1 = *(const s16x8*)(gK + (kt+2)*4096 + 8);
      }
      f32x4 a = {0.f,0.f,0.f,0.f};
#pragma unroll
      for (int kk=0;kk<2;kk++){
        s16x8 kf = frag64(myTs, l15, kk*4+lg);
        a = MF(kf, qfu[kk], a);               // D[k][q]
      }
      const int kb2 = kt*64 + sub*16 + lg*4;
      const u32 w0 = stash[kt*2], w1 = stash[kt*2+1];
      const float v0 = a[0] + bitsf(w0<<16);
      const float v1 = a[1] + bitsf(w0 & 0xffff0000u);
      const float v2 = a[2] + bitsf(w1<<16);
      const float v3 = a[3] + bitsf(w1 & 0xffff0000u);
      rmax = fmaxf(rmax, fmaxf(fmaxf(v0,v1), fmaxf(v2,v3)));
      s16x4 o;
      o[0]=(short)f2bf(v0); o[1]=(short)f2bf(v1);
      o[2]=(short)f2bf(v2); o[3]=(short)f2bf(v3);
      *(s16x4*)(sc + qi*1024 + SC_SLOT(qi, kb2>>3)*8 + (kb2&4)) = o;
    }
  }
  // in-wave reduce over lg, write per-wave per-qi max into own slice (K data dead)
  rmax = fmaxf(rmax, __shfl_xor(rmax,16));
  rmax = fmaxf(rmax, __shfl_xor(rmax,32));
  if (lane < 16) myTsF[l15] = rmax;

  __syncthreads();                            // B3: scores+pmax ready

  // ---- hoisted: V tile 0/1 prefetch (hide under softmax VALU)
  s16x8 va0 = *(const s16x8*)(gV);
  s16x8 va1 = *(const s16x8*)(gV + 8);
  s16x8 vb0 = *(const s16x8*)(gV + 64);
  s16x8 vb1 = *(const s16x8*)(gV + 64 + 8);

  // ---- softmax: max from slice partials; single exp+sum sweep
  {
    const int row = t>>4, c = t&15;
    const int qbR = row>>4, rl = row&15;
    float mx =            ((const float*)(Ts + (qbR  )*1024))[rl];
    mx = fmaxf(mx, ((const float*)(Ts + (qbR+2)*1024))[rl]);
    mx = fmaxf(mx, ((const float*)(Ts + (qbR+4)*1024))[rl]);
    mx = fmaxf(mx, ((const float*)(Ts + (qbR+6)*1024))[rl]);
    const float S2 = 0.063762029f;            // (1/sqrt(512)) * log2(e)
    const float nm = -mx * S2;
    float sum = 0.f;
#pragma unroll
    for (int i=0;i<8;i++){
      const int slot = c + 16*i;
      u16* p = sc + row*1024 + SC_SLOT(row,slot)*8;
      s16x8 v = *(const s16x8*)p;
      s16x8 o;
#pragma unroll
      for (int j2=0;j2<8;j2++){
        float e = exp2f(__builtin_fmaf(bf2f((u16)v[j2]), S2, nm));
        sum += e; o[j2] = (short)f2bf(e);
      }
      *(s16x8*)p = o;
    }
    sum += __shfl_xor(sum,1); sum += __shfl_xor(sum,2);
    sum += __shfl_xor(sum,4); sum += __shfl_xor(sum,8);
    if (c==0) ((float*)(Ts + (t>>6)*1024))[16 + (row&3)] = 1.0f/sum;
  }

  __syncthreads();                            // B4: stats visible
  const float inv = ((const float*)(Ts + (qi>>2)*1024))[16 + (qi&3)];
  __syncthreads();                            // B5: inv read -> slices reusable

  // ---- PV: D[d][q] = sum_k V^T[d][k] P^T[k][q]; NO barriers
  f32x4 accC = {0.f,0.f,0.f,0.f};
  {
#pragma unroll
    for (int kt=0; kt<16; ++kt){
      *(s16x8*)tw0 = va0;
      *(s16x8*)tw1 = va1;
      va0 = vb0; va1 = vb1;
      if (kt+2<16){
        vb0 = *(const s16x8*)(gV + (kt+2)*64);
        vb1 = *(const s16x8*)(gV + (kt+2)*64 + 8);
      }
#pragma unroll
      for (int kk=0;kk<2;kk++){
        const int slotk = kk*4 + lg;
        s16x8 vf = frag64(myTs, l15, slotk);
        const int slot = kt*8 + slotk;
        s16x8 pfr = *(const s16x8*)(sc + qi*1024 + SC_SLOT(qi,slot)*8);
        accC = MF(vf, pfr, accC);
      }
    }
  }
  {
    const int d0 = sub*16 + lg*4;
    s16x4 o;
#pragma unroll
    for (int r=0;r<4;r++) o[r] = (short)f2bf(accC[r]*inv);
    *(s16x4*)(Ctx_ + (q0+qi)*64 + d0) = o;
  }
}

// ---------------- output projection ----------------
__global__ __launch_bounds__(256,2) void k_out(
  const u16* __restrict__ Ctx, const u16* __restrict__ WT,
  const float* __restrict__ bo, float* __restrict__ Out)
{
  const u16* W = WT + 4*262144;
  const int m0 = blockIdx.y*128, n0 = blockIdx.x*128;
  const int b = m0>>10, s0 = m0&1023;
  __shared__ u16 As[128*64];
  __shared__ u16 Bs[128*64];
  const int t = threadIdx.x, lane = t&63, w = t>>6;
  const int wm = w&1, wn = w>>1;
  f32x4 acc[4][4];
#pragma unroll
  for (int i=0;i<4;i++)
#pragma unroll
    for (int j=0;j<4;j++) acc[i][j] = (f32x4){0.f,0.f,0.f,0.f};

  for (int kt=0; kt<8; ++kt){
    const int k0 = kt*64, hh = kt;
    __syncthreads();
#pragma unroll
    for (int i=0;i<4;i++){
      int id = t + 256*i; int row = id>>3, slot = id&7;
      s16x8 v = *(const s16x8*)(Ctx + ((b*8+hh)*1024 + s0 + row)*64 + slot*8);
      *(s16x8*)(As + row*64 + ((slot^(row&7))<<3)) = v;
    }
#pragma unroll
    for (int i=0;i<4;i++){
      int id = t + 256*i; int row = id>>3, slot = id&7;
      s16x8 v = *(const s16x8*)(W + (n0+row)*512 + k0 + slot*8);
      *(s16x8*)(Bs + row*64 + ((slot^(row&7))<<3)) = v;
    }
    __syncthreads();
#pragma unroll
    for (int kk=0;kk<2;kk++){
      const int slotk = kk*4 + (lane>>4);
      s16x8 xf[4], wf[4];
#pragma unroll
      for (int j=0;j<4;j++){ int r = wm*64 + j*16 + (lane&15); xf[j] = frag64(As, r, slotk); }
#pragma unroll
      for (int i=0;i<4;i++){ int r = wn*64 + i*16 + (lane&15); wf[i] = frag64(Bs, r, slotk); }
#pragma unroll
      for (int i=0;i<4;i++)
#pragma unroll
        for (int j=0;j<4;j++) acc[i][j] = MF(wf[i], xf[j], acc[i][j]);
    }
  }
#pragma unroll
  for (int i=0;i<4;i++){
    const int n = n0 + wn*64 + i*16 + ((lane>>4)<<2);
    f32x4 bo4 = *(const f32x4*)(bo + n);
#pragma unroll
    for (int j=0;j<4;j++){
      const int m = m0 + wm*64 + j*16 + (lane&15);
      f32x4 o = acc[i][j] + bo4;
      *(f32x4*)(Out + m*512 + n) = o;
    }
  }
}

extern "C" void kernel_launch(void* const* d_in, const int* in_sizes, int n_in,
                              void* d_out, int out_size, void* d_ws, size_t ws_size,
                              hipStream_t stream)
{
  const float* query = (const float*)d_in[0];
  const float* key   = (const float*)d_in[1];
  const float* value = (const float*)d_in[2];
  const float* pos   = (const float*)d_in[3];
  const float* Wq = (const float*)d_in[4];
  const float* bq = (const float*)d_in[5];
  const float* Wk = (const float*)d_in[6];
  const float* bk = (const float*)d_in[7];
  const float* Wv = (const float*)d_in[8];
  const float* bv = (const float*)d_in[9];
  const float* Wp = (const float*)d_in[10];
  const float* Wo = (const float*)d_in[11];
  const float* bo = (const float*)d_in[12];
  const float* ub = (const float*)d_in[13];
  const float* vb = (const float*)d_in[14];
  float* Out = (float*)d_out;

  u16* ws  = (u16*)d_ws;
  u16* WT  = ws;                       // 5 * 262144
  u16* Qu  = ws + 1310720;             // each tensor: 8*8*1024*64 = 4194304
  u16* Qv  = Qu + 4194304;
  u16* Kb  = Qv + 4194304;
  u16* Pb  = Kb + 4194304;
  u16* Vt  = Pb + 4194304;
  u16* Ctx = Vt + 4194304;

  k_prep<<<dim3(320),  dim3(256), 0, stream>>>(Wq,Wk,Wv,Wp,Wo,WT);
  k_proj<<<dim3(1024), dim3(256), 0, stream>>>(query,key,value,pos,WT,bq,bk,bv,ub,vb,Qu,Qv,Kb,Pb,Vt);
  k_attn<<<dim3(2048), dim3(512), 0, stream>>>(Qu,Qv,Kb,Pb,Vt,Ctx);
  k_out<<<dim3(4,64),  dim3(256), 0, stream>>>(Ctx,WT,bo,Out);
}

// Round 13
// 200.604 us; speedup vs baseline: 1.1291x; 1.1291x over previous
//
#include <hip/hip_runtime.h>
#include <hip/hip_bf16.h>

typedef unsigned short u16;
typedef unsigned int u32;
typedef __attribute__((ext_vector_type(4))) float f32x4;
typedef __attribute__((ext_vector_type(8))) short s16x8;
typedef __attribute__((ext_vector_type(4))) short s16x4;

#define DEV static __device__ __forceinline__

DEV u16 f2bf(float f){ return __builtin_bit_cast(u16, __float2bfloat16(f)); }
DEV float bf2f(u16 v){ union{u32 u;float f;}x; x.u = ((u32)v)<<16; return x.f; }
DEV float bitsf(u32 u){ union{u32 u;float f;}x; x.u = u; return x.f; }

DEV f32x4 MF(s16x8 a, s16x8 b, f32x4 c){ return __builtin_amdgcn_mfma_f32_16x16x32_bf16(a,b,c,0,0,0); }

DEV s16x8 frag64(const u16* lds, int row, int slot){
  return *(const s16x8*)(lds + row*64 + ((slot ^ (row&7))<<3));
}

// ---------------- prep: W[k][n] f32 -> WT[n][k] bf16, 5 matrices ----------------
__global__ __launch_bounds__(256) void k_prep(
  const float* __restrict__ Wq, const float* __restrict__ Wk, const float* __restrict__ Wv,
  const float* __restrict__ Wp, const float* __restrict__ Wo, u16* __restrict__ WT)
{
  const int bx = blockIdx.x; const int mat = bx>>6, tile = bx&63;
  const float* W = (mat==0)?Wq:(mat==1)?Wk:(mat==2)?Wv:(mat==3)?Wp:Wo;
  u16* dst = WT + mat*262144;
  const int k0 = (tile>>3)<<6, n0 = (tile&7)<<6;
  __shared__ u16 L[64*68];
  const int t = threadIdx.x;
#pragma unroll
  for (int i=0;i<4;i++){
    int id = t + 256*i; int row = id>>4, c4 = (id&15)<<2;
    float4 v = *(const float4*)(W + (k0+row)*512 + n0 + c4);
    s16x4 o; o[0]=(short)f2bf(v.x); o[1]=(short)f2bf(v.y); o[2]=(short)f2bf(v.z); o[3]=(short)f2bf(v.w);
    *(s16x4*)(L + row*68 + c4) = o;
  }
  __syncthreads();
#pragma unroll
  for (int i=0;i<2;i++){
    int id = t + 256*i; int nl = id>>3, slot = id&7;
    s16x8 v;
#pragma unroll
    for (int j=0;j<8;j++) v[j] = (short)L[(slot*8+j)*68 + nl];
    *(s16x8*)(dst + (n0+nl)*512 + k0 + slot*8) = v;
  }
}

// ---------------- projections (1D grid, XCD-chunked) ----------------
__global__ __launch_bounds__(256,2) void k_proj(
  const float* __restrict__ Xq, const float* __restrict__ Xk,
  const float* __restrict__ Xv, const float* __restrict__ Xp,
  const u16* __restrict__ WT,
  const float* __restrict__ bq, const float* __restrict__ bk, const float* __restrict__ bv,
  const float* __restrict__ ub, const float* __restrict__ vb,
  u16* __restrict__ Qu, u16* __restrict__ Qv, u16* __restrict__ Kb,
  u16* __restrict__ Pb, u16* __restrict__ Vt)
{
  const int Lb = blockIdx.x;
  const int xcd = Lb & 7, li = Lb >> 3;        // li 0..127
  const int n0  = (li & 3) * 128;
  const int job = (li >> 2) & 3;
  const int m0  = (xcd*8 + (li >> 4)) * 128;
  const float* X = (job==0)?Xq:(job==1)?Xk:(job==2)?Xp:Xv;
  const int wsel = (job==0)?0:(job==1)?1:(job==2)?3:2;
  const u16* W = WT + wsel*262144;
  __shared__ u16 As[128*64];
  __shared__ u16 Bs[128*64];
  const int t = threadIdx.x, lane = t&63, w = t>>6;
  const int wm = w&1, wn = w>>1;
  f32x4 acc[4][4];
#pragma unroll
  for (int i=0;i<4;i++)
#pragma unroll
    for (int j=0;j<4;j++) acc[i][j] = (f32x4){0.f,0.f,0.f,0.f};

  for (int kt=0; kt<8; ++kt){
    const int k0 = kt*64;
    __syncthreads();
#pragma unroll
    for (int i=0;i<8;i++){
      int id = t + 256*i; int row = id>>4; int c4 = (id&15)<<2;
      float4 v = *(const float4*)(X + (m0+row)*512 + k0 + c4);
      s16x4 o; o[0]=(short)f2bf(v.x); o[1]=(short)f2bf(v.y); o[2]=(short)f2bf(v.z); o[3]=(short)f2bf(v.w);
      *(s16x4*)(As + row*64 + ((((c4>>3)^(row&7))<<3) + (c4&4))) = o;
    }
#pragma unroll
    for (int i=0;i<4;i++){
      int id = t + 256*i; int row = id>>3, slot = id&7;
      s16x8 v = *(const s16x8*)(W + (n0+row)*512 + k0 + slot*8);
      *(s16x8*)(Bs + row*64 + ((slot^(row&7))<<3)) = v;
    }
    __syncthreads();
#pragma unroll
    for (int kk=0;kk<2;kk++){
      const int slotk = kk*4 + (lane>>4);
      s16x8 xf[4], wf[4];
#pragma unroll
      for (int j=0;j<4;j++){ int r = wm*64 + j*16 + (lane&15); xf[j] = frag64(As, r, slotk); }
#pragma unroll
      for (int i=0;i<4;i++){ int r = wn*64 + i*16 + (lane&15); wf[i] = frag64(Bs, r, slotk); }
      if (job != 3){
#pragma unroll
        for (int i=0;i<4;i++)
#pragma unroll
          for (int j=0;j<4;j++) acc[i][j] = MF(wf[i], xf[j], acc[i][j]);   // D[n][m]
      } else {
#pragma unroll
        for (int i=0;i<4;i++)
#pragma unroll
          for (int j=0;j<4;j++) acc[i][j] = MF(xf[i], wf[j], acc[i][j]);   // D[m][n]
      }
    }
  }

  const int b = m0>>10;
  if (job != 3){
#pragma unroll
    for (int i=0;i<4;i++){
      const int n = n0 + wn*64 + i*16 + ((lane>>4)<<2);
      const int hh = n>>6, d = n&63;
      f32x4 b1 = {0.f,0.f,0.f,0.f}, b2 = {0.f,0.f,0.f,0.f};
      if (job==0){
        f32x4 q4 = *(const f32x4*)(bq+n); f32x4 u4 = *(const f32x4*)(ub+n); f32x4 v4 = *(const f32x4*)(vb+n);
        b1 = q4 + u4; b2 = q4 + v4;
      } else if (job==1){
        b1 = *(const f32x4*)(bk+n);
      }
#pragma unroll
      for (int j=0;j<4;j++){
        const int m = m0 + wm*64 + j*16 + (lane&15);
        const int s = m&1023;
        const int off = ((b*8+hh)*1024 + s)*64 + d;
        f32x4 a = acc[i][j];
        s16x4 o1;
#pragma unroll
        for (int r=0;r<4;r++) o1[r] = (short)f2bf(a[r]+b1[r]);
        if (job==0){
          *(s16x4*)(Qu+off) = o1;
          s16x4 o2;
#pragma unroll
          for (int r=0;r<4;r++) o2[r] = (short)f2bf(a[r]+b2[r]);
          *(s16x4*)(Qv+off) = o2;
        } else if (job==1) *(s16x4*)(Kb+off) = o1;
        else               *(s16x4*)(Pb+off) = o1;
      }
    }
  } else {
#pragma unroll
    for (int j=0;j<4;j++){
      const int n = n0 + wn*64 + j*16 + (lane&15);
      const int hh = n>>6, d = n&63;
      const float bvn = bv[n];
#pragma unroll
      for (int i=0;i<4;i++){
        const int m = m0 + wm*64 + i*16 + ((lane>>4)<<2);
        const int s = m&1023;
        f32x4 a = acc[i][j];
        s16x4 o;
#pragma unroll
        for (int r=0;r<4;r++) o[r] = (short)f2bf(a[r]+bvn);
        *(s16x4*)(Vt + ((b*8+hh)*64 + d)*1024 + s) = o;
      }
    }
  }
}

// ---------------- fused rel-shift attention: barrier-free, 16-row q-blocks ----------------
// 512 thr / 8 waves per 16 q-rows; private 2KB staging slices -> no k-loop barriers.
// LDS ~53.3 KB -> 3 blocks/CU (24 waves). Phase1: waves 0-3 primary PS rows 0..15,
// waves 4-7 overlap row 16 (phys row 0 head, jj<=1006-q0; row 0 tail jj>=1023-q0).
// Phase2/PV: wave pairs (whalf) split k-tiles; PV partials reduced via LDS scratch.
#define SC_SLOT(q, slot) ((((slot)) & ~7) | ((((slot))&7) ^ ((q)&7)))

__global__ __launch_bounds__(512,6) void k_attn(
  const u16* __restrict__ Qu, const u16* __restrict__ Qv,
  const u16* __restrict__ Kb, const u16* __restrict__ Pb,
  const u16* __restrict__ Vt, u16* __restrict__ Ctx)
{
  const int Lb = blockIdx.x;
  const int xcd = Lb & 7, li = Lb >> 3;       // 8 bh per XCD -> L2-resident K/P/V
  const int bh = xcd*8 + (li>>6);
  const int qb = li & 63;
  const int q0 = qb*16;
  const u16* Qu_ = Qu + bh*65536;
  const u16* Qv_ = Qv + bh*65536;
  const u16* Kb_ = Kb + bh*65536;
  const u16* Pb_ = Pb + bh*65536;
  const u16* Vt_ = Vt + bh*65536;
  u16* Ctx_ = Ctx + bh*65536;
  __shared__ u16 sc[16*1024];                 // 32768 B
  __shared__ u16 Ts[8*1024];                  // 16384 B: 8 private wave slices
  __shared__ float scratch[1024];             // 4096 B: pmax then PV partials
  __shared__ float stats[16];
  const int t = threadIdx.x, lane = t&63, w = t>>6;
  const int l15 = lane&15, lg = lane>>4;
  const int whalf = w>>2, sub = w&3;
  const int qi = l15;
  const int q  = q0 + qi;
  u16* myTs = Ts + w*1024;

  // per-lane slice staging coords: 2 chunks (row srowL, slots ssl0, ssl0+1)
  const int srowL = lane>>2;                  // 0..15
  const int ssl0  = (lane&3)<<1;              // 0,2,4,6
  u16* tw0 = myTs + srowL*64 + (((ssl0  )^(srowL&7))<<3);
  u16* tw1 = myTs + srowL*64 + (((ssl0+1)^(srowL&7))<<3);
  const u16* gP = Pb_ + (sub*16 + srowL)*64 + ssl0*8;                       // jtp = sub
  const u16* gK = Kb_ + ((whalf*64) + sub*16 + srowL)*64 + ssl0*8;          // tile kt=whalf
  const u16* gV = Vt_ + (sub*16 + srowL)*1024 + whalf*64 + ssl0*8;

  // ---- P tile 0/1 prefetch (latency hides under Qv preloads)
  s16x8 pa0 = *(const s16x8*)(gP);
  s16x8 pa1 = *(const s16x8*)(gP + 8);
  s16x8 pb0 = *(const s16x8*)(gP + 4096);
  s16x8 pb1 = *(const s16x8*)(gP + 4096 + 8);

  // ---- preload Qv fragments: waves 0-3 primary rows q0+l15; 4-7 overlap rows q0+1+l15
  s16x8 qvf[2];
#pragma unroll
  for (int kk=0;kk<2;kk++){
    int rr = whalf ? (q0 + 1 + l15) : (q0 + l15);
    if (rr > 1023) rr = 1023;                 // q0=1008 edge: row16 never stored
    qvf[kk] = *(const s16x8*)(Qv_ + rr*64 + (kk*4+lg)*8);
  }

  // ---- phase 1: raw PS rows -> sc (swzA); NO barriers (private slices)
  {
#pragma unroll
    for (int u=0; u<16; ++u){
      *(s16x8*)tw0 = pa0;
      *(s16x8*)tw1 = pa1;
      pa0 = pb0; pa1 = pb1;
      if (u+2<16){
        pb0 = *(const s16x8*)(gP + (u+2)*4096);
        pb1 = *(const s16x8*)(gP + (u+2)*4096 + 8);
      }
      f32x4 ps = {0.f,0.f,0.f,0.f};
#pragma unroll
      for (int kk=0;kk<2;kk++){
        s16x8 pf = frag64(myTs, l15, kk*4+lg);
        ps = MF(pf, qvf[kk], ps);             // PS[qrow][j=u*64+sub*16+lg*4+r]
      }
      const int j0 = u*64 + sub*16 + lg*4;
      if (whalf == 0){
        const int prow = l15;
        if (prow){
          s16x4 o;
#pragma unroll
          for (int r=0;r<4;r++) o[r] = (short)f2bf(ps[r]);
          *(s16x4*)(sc + prow*1024 + ((((j0>>2) ^ ((prow&15)<<1)))<<2)) = o;
        } else {
          // row 0 tail only (head of phys row 0 belongs to PS row 16)
#pragma unroll
          for (int r=0;r<4;r++){
            const int jj = j0 + r;
            if (jj >= 1023 - q0) sc[jj] = f2bf(ps[r]);
          }
        }
      } else {
        if (l15 == 15){                       // keep PS row q0+16 -> phys row 0 head
#pragma unroll
          for (int r=0;r<4;r++){
            const int jj = j0 + r;
            if (jj <= 1006 - q0) sc[jj] = f2bf(ps[r]);
          }
        }
      }
    }
  }

  __syncthreads();                            // B1: PS complete -> gather may read

  // ---- hoisted: Qu fragments + K tile prefetch (hide under gather VALU)
  s16x8 qfu[2];
#pragma unroll
  for (int kk=0;kk<2;kk++)
    qfu[kk] = *(const s16x8*)(Qu_ + q*64 + (kk*4+lg)*8);
  s16x8 ka0 = *(const s16x8*)(gK);
  s16x8 ka1 = *(const s16x8*)(gK + 8);
  s16x8 kb0 = *(const s16x8*)(gK + 8192);
  s16x8 kb1 = *(const s16x8*)(gK + 8192 + 8);

  // ---- gather pre-pass: rel-shifted pos for this thread's 32 phase-2 cells
  u32 stash[16];
#pragma unroll
  for (int i=0;i<8;i++){
    const int ktb = (2*i + whalf)*64 + sub*16 + lg*4;
#pragma unroll
    for (int rp=0; rp<2; ++rp){
      u32 wv = 0;
#pragma unroll
      for (int hh=0; hh<2; ++hh){
        const int k = ktb + rp*2 + hh;
        const int above = (k > q) ? 1 : 0;
        int jj = above ? (k - q - 2) : (1023 - q + k);
        const bool zero = (k == q+1);
        if (jj < 0) jj = 0;
        const int phys = (qi + above) & 15;
        const int addr = phys*1024 + ((((jj>>2) ^ ((phys&15)<<1)))<<2) + (jj&3);
        u32 v = zero ? 0u : (u32)sc[addr];
        wv |= v << (16*hh);
      }
      stash[i*2+rp] = wv;
    }
  }

  __syncthreads();                            // B2: gather done -> sc may be overwritten

  // ---- phase 2: content Qu.K^T + stash -> sc (swzB); NO barriers
  float rmax = -1e30f;
  {
#pragma unroll
    for (int i=0;i<8;i++){
      *(s16x8*)tw0 = ka0;
      *(s16x8*)tw1 = ka1;
      ka0 = kb0; ka1 = kb1;
      if (i+2<8){
        kb0 = *(const s16x8*)(gK + (i+2)*8192);
        kb1 = *(const s16x8*)(gK + (i+2)*8192 + 8);
      }
      f32x4 a = {0.f,0.f,0.f,0.f};
#pragma unroll
      for (int kk=0;kk<2;kk++){
        s16x8 kf = frag64(myTs, l15, kk*4+lg);
        a = MF(kf, qfu[kk], a);               // D[k][q]
      }
      const int kb2 = (2*i + whalf)*64 + sub*16 + lg*4;
      const u32 w0 = stash[i*2], w1 = stash[i*2+1];
      const float v0 = a[0] + bitsf(w0<<16);
      const float v1 = a[1] + bitsf(w0 & 0xffff0000u);
      const float v2 = a[2] + bitsf(w1<<16);
      const float v3 = a[3] + bitsf(w1 & 0xffff0000u);
      rmax = fmaxf(rmax, fmaxf(fmaxf(v0,v1), fmaxf(v2,v3)));
      s16x4 o;
      o[0]=(short)f2bf(v0); o[1]=(short)f2bf(v1);
      o[2]=(short)f2bf(v2); o[3]=(short)f2bf(v3);
      *(s16x4*)(sc + qi*1024 + SC_SLOT(qi, kb2>>3)*8 + (kb2&4)) = o;
    }
  }
  scratch[qi*32 + w*4 + lg] = rmax;           // pmax partials (512 floats)

  __syncthreads();                            // B3: scores+pmax ready

  // ---- hoisted: V tile prefetch (hide under softmax VALU)
  s16x8 va0 = *(const s16x8*)(gV);
  s16x8 va1 = *(const s16x8*)(gV + 8);
  s16x8 vb0 = *(const s16x8*)(gV + 128);
  s16x8 vb1 = *(const s16x8*)(gV + 128 + 8);

  // ---- softmax: 32 threads/row; single exp+sum sweep
  {
    const int row = t>>5, c = t&31;
    float mx = scratch[row*32 + c];
    mx = fmaxf(mx, __shfl_xor(mx,1));
    mx = fmaxf(mx, __shfl_xor(mx,2));
    mx = fmaxf(mx, __shfl_xor(mx,4));
    mx = fmaxf(mx, __shfl_xor(mx,8));
    mx = fmaxf(mx, __shfl_xor(mx,16));
    const float S2 = 0.063762029f;            // (1/sqrt(512)) * log2(e)
    const float nm = -mx * S2;
    float sum = 0.f;
#pragma unroll
    for (int i=0;i<4;i++){
      const int slot = c + 32*i;
      u16* p = sc + row*1024 + SC_SLOT(row,slot)*8;
      s16x8 v = *(const s16x8*)p;
      s16x8 o;
#pragma unroll
      for (int j2=0;j2<8;j2++){
        float e = exp2f(__builtin_fmaf(bf2f((u16)v[j2]), S2, nm));
        sum += e; o[j2] = (short)f2bf(e);
      }
      *(s16x8*)p = o;
    }
    sum += __shfl_xor(sum,1); sum += __shfl_xor(sum,2);
    sum += __shfl_xor(sum,4); sum += __shfl_xor(sum,8);
    sum += __shfl_xor(sum,16);
    if (c==0) stats[row] = 1.0f/sum;
  }

  __syncthreads();                            // B4: probs+stats visible

  // ---- PV: D[d][q]; pair waves split k-tiles; NO barriers in loop
  f32x4 accC = {0.f,0.f,0.f,0.f};
  {
#pragma unroll
    for (int i=0;i<8;i++){
      *(s16x8*)tw0 = va0;
      *(s16x8*)tw1 = va1;
      va0 = vb0; va1 = vb1;
      if (i+2<8){
        vb0 = *(const s16x8*)(gV + (i+2)*128);
        vb1 = *(const s16x8*)(gV + (i+2)*128 + 8);
      }
      const int kt = 2*i + whalf;
#pragma unroll
      for (int kk=0;kk<2;kk++){
        const int slotk = kk*4 + lg;
        s16x8 vf = frag64(myTs, l15, slotk);
        const int slot = kt*8 + slotk;
        s16x8 pfr = *(const s16x8*)(sc + qi*1024 + SC_SLOT(qi,slot)*8);
        accC = MF(vf, pfr, accC);
      }
    }
  }
  // pair reduce: whalf 0 writes partials (scratch safe after B4), whalf 1 adds+stores
  if (whalf == 0){
#pragma unroll
    for (int r=0;r<4;r++) scratch[(sub*16 + lg*4 + r)*16 + l15] = accC[r];
  }
  __syncthreads();                            // B5: partials ready
  if (whalf == 1){
    const float inv = stats[l15];
    const int d0 = sub*16 + lg*4;
    s16x4 o;
#pragma unroll
    for (int r=0;r<4;r++){
      const float vsum = accC[r] + scratch[(d0 + r)*16 + l15];
      o[r] = (short)f2bf(vsum*inv);
    }
    *(s16x4*)(Ctx_ + (q0+qi)*64 + d0) = o;
  }
}

// ---------------- output projection ----------------
__global__ __launch_bounds__(256,2) void k_out(
  const u16* __restrict__ Ctx, const u16* __restrict__ WT,
  const float* __restrict__ bo, float* __restrict__ Out)
{
  const u16* W = WT + 4*262144;
  const int m0 = blockIdx.y*128, n0 = blockIdx.x*128;
  const int b = m0>>10, s0 = m0&1023;
  __shared__ u16 As[128*64];
  __shared__ u16 Bs[128*64];
  const int t = threadIdx.x, lane = t&63, w = t>>6;
  const int wm = w&1, wn = w>>1;
  f32x4 acc[4][4];
#pragma unroll
  for (int i=0;i<4;i++)
#pragma unroll
    for (int j=0;j<4;j++) acc[i][j] = (f32x4){0.f,0.f,0.f,0.f};

  for (int kt=0; kt<8; ++kt){
    const int k0 = kt*64, hh = kt;
    __syncthreads();
#pragma unroll
    for (int i=0;i<4;i++){
      int id = t + 256*i; int row = id>>3, slot = id&7;
      s16x8 v = *(const s16x8*)(Ctx + ((b*8+hh)*1024 + s0 + row)*64 + slot*8);
      *(s16x8*)(As + row*64 + ((slot^(row&7))<<3)) = v;
    }
#pragma unroll
    for (int i=0;i<4;i++){
      int id = t + 256*i; int row = id>>3, slot = id&7;
      s16x8 v = *(const s16x8*)(W + (n0+row)*512 + k0 + slot*8);
      *(s16x8*)(Bs + row*64 + ((slot^(row&7))<<3)) = v;
    }
    __syncthreads();
#pragma unroll
    for (int kk=0;kk<2;kk++){
      const int slotk = kk*4 + (lane>>4);
      s16x8 xf[4], wf[4];
#pragma unroll
      for (int j=0;j<4;j++){ int r = wm*64 + j*16 + (lane&15); xf[j] = frag64(As, r, slotk); }
#pragma unroll
      for (int i=0;i<4;i++){ int r = wn*64 + i*16 + (lane&15); wf[i] = frag64(Bs, r, slotk); }
#pragma unroll
      for (int i=0;i<4;i++)
#pragma unroll
        for (int j=0;j<4;j++) acc[i][j] = MF(wf[i], xf[j], acc[i][j]);
    }
  }
#pragma unroll
  for (int i=0;i<4;i++){
    const int n = n0 + wn*64 + i*16 + ((lane>>4)<<2);
    f32x4 bo4 = *(const f32x4*)(bo + n);
#pragma unroll
    for (int j=0;j<4;j++){
      const int m = m0 + wm*64 + j*16 + (lane&15);
      f32x4 o = acc[i][j] + bo4;
      *(f32x4*)(Out + m*512 + n) = o;
    }
  }
}

extern "C" void kernel_launch(void* const* d_in, const int* in_sizes, int n_in,
                              void* d_out, int out_size, void* d_ws, size_t ws_size,
                              hipStream_t stream)
{
  const float* query = (const float*)d_in[0];
  const float* key   = (const float*)d_in[1];
  const float* value = (const float*)d_in[2];
  const float* pos   = (const float*)d_in[3];
  const float* Wq = (const float*)d_in[4];
  const float* bq = (const float*)d_in[5];
  const float* Wk = (const float*)d_in[6];
  const float* bk = (const float*)d_in[7];
  const float* Wv = (const float*)d_in[8];
  const float* bv = (const float*)d_in[9];
  const float* Wp = (const float*)d_in[10];
  const float* Wo = (const float*)d_in[11];
  const float* bo = (const float*)d_in[12];
  const float* ub = (const float*)d_in[13];
  const float* vb = (const float*)d_in[14];
  float* Out = (float*)d_out;

  u16* ws  = (u16*)d_ws;
  u16* WT  = ws;                       // 5 * 262144
  u16* Qu  = ws + 1310720;             // each tensor: 8*8*1024*64 = 4194304
  u16* Qv  = Qu + 4194304;
  u16* Kb  = Qv + 4194304;
  u16* Pb  = Kb + 4194304;
  u16* Vt  = Pb + 4194304;
  u16* Ctx = Vt + 4194304;

  k_prep<<<dim3(320),  dim3(256), 0, stream>>>(Wq,Wk,Wv,Wp,Wo,WT);
  k_proj<<<dim3(1024), dim3(256), 0, stream>>>(query,key,value,pos,WT,bq,bk,bv,ub,vb,Qu,Qv,Kb,Pb,Vt);
  k_attn<<<dim3(4096), dim3(512), 0, stream>>>(Qu,Qv,Kb,Pb,Vt,Ctx);
  k_out<<<dim3(4,64),  dim3(256), 0, stream>>>(Ctx,WT,bo,Out);
}

// Round 14
// 175.492 us; speedup vs baseline: 1.2906x; 1.1431x over previous
//
#include <hip/hip_runtime.h>
#include <hip/hip_bf16.h>

typedef unsigned short u16;
typedef unsigned int u32;
typedef __attribute__((ext_vector_type(4))) float f32x4;
typedef __attribute__((ext_vector_type(8))) short s16x8;
typedef __attribute__((ext_vector_type(4))) short s16x4;

#define DEV static __device__ __forceinline__

DEV u16 f2bf(float f){ return __builtin_bit_cast(u16, __float2bfloat16(f)); }
DEV float bf2f(u16 v){ union{u32 u;float f;}x; x.u = ((u32)v)<<16; return x.f; }
DEV float bitsf(u32 u){ union{u32 u;float f;}x; x.u = u; return x.f; }

DEV f32x4 MF(s16x8 a, s16x8 b, f32x4 c){ return __builtin_amdgcn_mfma_f32_16x16x32_bf16(a,b,c,0,0,0); }

DEV s16x8 frag64(const u16* lds, int row, int slot){
  return *(const s16x8*)(lds + row*64 + ((slot ^ (row&7))<<3));
}

// ---------------- prep: W[k][n] f32 -> WT[n][k] bf16, 5 matrices ----------------
__global__ __launch_bounds__(256) void k_prep(
  const float* __restrict__ Wq, const float* __restrict__ Wk, const float* __restrict__ Wv,
  const float* __restrict__ Wp, const float* __restrict__ Wo, u16* __restrict__ WT)
{
  const int bx = blockIdx.x; const int mat = bx>>6, tile = bx&63;
  const float* W = (mat==0)?Wq:(mat==1)?Wk:(mat==2)?Wv:(mat==3)?Wp:Wo;
  u16* dst = WT + mat*262144;
  const int k0 = (tile>>3)<<6, n0 = (tile&7)<<6;
  __shared__ u16 L[64*68];
  const int t = threadIdx.x;
#pragma unroll
  for (int i=0;i<4;i++){
    int id = t + 256*i; int row = id>>4, c4 = (id&15)<<2;
    float4 v = *(const float4*)(W + (k0+row)*512 + n0 + c4);
    s16x4 o; o[0]=(short)f2bf(v.x); o[1]=(short)f2bf(v.y); o[2]=(short)f2bf(v.z); o[3]=(short)f2bf(v.w);
    *(s16x4*)(L + row*68 + c4) = o;
  }
  __syncthreads();
#pragma unroll
  for (int i=0;i<2;i++){
    int id = t + 256*i; int nl = id>>3, slot = id&7;
    s16x8 v;
#pragma unroll
    for (int j=0;j<8;j++) v[j] = (short)L[(slot*8+j)*68 + nl];
    *(s16x8*)(dst + (n0+nl)*512 + k0 + slot*8) = v;
  }
}

// ---------------- projections (1D grid, XCD-chunked) ----------------
__global__ __launch_bounds__(256,2) void k_proj(
  const float* __restrict__ Xq, const float* __restrict__ Xk,
  const float* __restrict__ Xv, const float* __restrict__ Xp,
  const u16* __restrict__ WT,
  const float* __restrict__ bq, const float* __restrict__ bk, const float* __restrict__ bv,
  const float* __restrict__ ub, const float* __restrict__ vb,
  u16* __restrict__ Qu, u16* __restrict__ Qv, u16* __restrict__ Kb,
  u16* __restrict__ Pb, u16* __restrict__ Vt)
{
  const int Lb = blockIdx.x;
  const int xcd = Lb & 7, li = Lb >> 3;        // li 0..127
  const int n0  = (li & 3) * 128;
  const int job = (li >> 2) & 3;
  const int m0  = (xcd*8 + (li >> 4)) * 128;
  const float* X = (job==0)?Xq:(job==1)?Xk:(job==2)?Xp:Xv;
  const int wsel = (job==0)?0:(job==1)?1:(job==2)?3:2;
  const u16* W = WT + wsel*262144;
  __shared__ u16 As[128*64];
  __shared__ u16 Bs[128*64];
  const int t = threadIdx.x, lane = t&63, w = t>>6;
  const int wm = w&1, wn = w>>1;
  f32x4 acc[4][4];
#pragma unroll
  for (int i=0;i<4;i++)
#pragma unroll
    for (int j=0;j<4;j++) acc[i][j] = (f32x4){0.f,0.f,0.f,0.f};

  for (int kt=0; kt<8; ++kt){
    const int k0 = kt*64;
    __syncthreads();
#pragma unroll
    for (int i=0;i<8;i++){
      int id = t + 256*i; int row = id>>4; int c4 = (id&15)<<2;
      float4 v = *(const float4*)(X + (m0+row)*512 + k0 + c4);
      s16x4 o; o[0]=(short)f2bf(v.x); o[1]=(short)f2bf(v.y); o[2]=(short)f2bf(v.z); o[3]=(short)f2bf(v.w);
      *(s16x4*)(As + row*64 + ((((c4>>3)^(row&7))<<3) + (c4&4))) = o;
    }
#pragma unroll
    for (int i=0;i<4;i++){
      int id = t + 256*i; int row = id>>3, slot = id&7;
      s16x8 v = *(const s16x8*)(W + (n0+row)*512 + k0 + slot*8);
      *(s16x8*)(Bs + row*64 + ((slot^(row&7))<<3)) = v;
    }
    __syncthreads();
#pragma unroll
    for (int kk=0;kk<2;kk++){
      const int slotk = kk*4 + (lane>>4);
      s16x8 xf[4], wf[4];
#pragma unroll
      for (int j=0;j<4;j++){ int r = wm*64 + j*16 + (lane&15); xf[j] = frag64(As, r, slotk); }
#pragma unroll
      for (int i=0;i<4;i++){ int r = wn*64 + i*16 + (lane&15); wf[i] = frag64(Bs, r, slotk); }
      if (job != 3){
#pragma unroll
        for (int i=0;i<4;i++)
#pragma unroll
          for (int j=0;j<4;j++) acc[i][j] = MF(wf[i], xf[j], acc[i][j]);   // D[n][m]
      } else {
#pragma unroll
        for (int i=0;i<4;i++)
#pragma unroll
          for (int j=0;j<4;j++) acc[i][j] = MF(xf[i], wf[j], acc[i][j]);   // D[m][n]
      }
    }
  }

  const int b = m0>>10;
  if (job != 3){
#pragma unroll
    for (int i=0;i<4;i++){
      const int n = n0 + wn*64 + i*16 + ((lane>>4)<<2);
      const int hh = n>>6, d = n&63;
      f32x4 b1 = {0.f,0.f,0.f,0.f}, b2 = {0.f,0.f,0.f,0.f};
      if (job==0){
        f32x4 q4 = *(const f32x4*)(bq+n); f32x4 u4 = *(const f32x4*)(ub+n); f32x4 v4 = *(const f32x4*)(vb+n);
        b1 = q4 + u4; b2 = q4 + v4;
      } else if (job==1){
        b1 = *(const f32x4*)(bk+n);
      }
#pragma unroll
      for (int j=0;j<4;j++){
        const int m = m0 + wm*64 + j*16 + (lane&15);
        const int s = m&1023;
        const int off = ((b*8+hh)*1024 + s)*64 + d;
        f32x4 a = acc[i][j];
        s16x4 o1;
#pragma unroll
        for (int r=0;r<4;r++) o1[r] = (short)f2bf(a[r]+b1[r]);
        if (job==0){
          *(s16x4*)(Qu+off) = o1;
          s16x4 o2;
#pragma unroll
          for (int r=0;r<4;r++) o2[r] = (short)f2bf(a[r]+b2[r]);
          *(s16x4*)(Qv+off) = o2;
        } else if (job==1) *(s16x4*)(Kb+off) = o1;
        else               *(s16x4*)(Pb+off) = o1;
      }
    }
  } else {
#pragma unroll
    for (int j=0;j<4;j++){
      const int n = n0 + wn*64 + j*16 + (lane&15);
      const int hh = n>>6, d = n&63;
      const float bvn = bv[n];
#pragma unroll
      for (int i=0;i<4;i++){
        const int m = m0 + wm*64 + i*16 + ((lane>>4)<<2);
        const int s = m&1023;
        f32x4 a = acc[i][j];
        s16x4 o;
#pragma unroll
        for (int r=0;r<4;r++) o[r] = (short)f2bf(a[r]+bvn);
        *(s16x4*)(Vt + ((b*8+hh)*64 + d)*1024 + s) = o;
      }
    }
  }
}

// ---------------- fused rel-shift attention (R11 proven-best) ----------------
// R9 structure + hoisted first-tile prefetches. sc 33 rows stride 1024, single
// Ts, 2-barrier staged loops, XCD bh-chunking, phase-2 f32 running max,
// single-sweep exp2 softmax. 78336 B LDS -> 2 blocks/CU.
#define SC_SLOT(q, slot) ((((slot)) & ~7) | ((((slot))&7) ^ ((q)&7)))

__global__ __launch_bounds__(512,2) void k_attn(
  const u16* __restrict__ Qu, const u16* __restrict__ Qv,
  const u16* __restrict__ Kb, const u16* __restrict__ Pb,
  const u16* __restrict__ Vt, u16* __restrict__ Ctx)
{
  const int Lb = blockIdx.x;
  const int xcd = Lb & 7, li = Lb >> 3;       // 8 bh per XCD -> L2-resident K/P/V
  const int bh = xcd*8 + (li>>5);
  const int qb = li & 31;
  const int q0 = qb*32;
  const u16* Qu_ = Qu + bh*65536;
  const u16* Qv_ = Qv + bh*65536;
  const u16* Kb_ = Kb + bh*65536;
  const u16* Pb_ = Pb + bh*65536;
  const u16* Vt_ = Vt + bh*65536;
  u16* Ctx_ = Ctx + bh*65536;
  __shared__ u16 sc[33*1024];
  __shared__ u16 Ts[4096];
  __shared__ float pmax[512];
  __shared__ float stats[32];
  const int t = threadIdx.x, lane = t&63, w = t>>6;
  const int l15 = lane&15, lg = lane>>4;
  const int qband = w&1, sub = w>>1;
  const int qi = qband*16 + l15;
  const int q  = q0 + qi;
  const int srow = t>>3, sslot = t&7;
  u16* tsw = Ts + srow*64 + ((sslot^(srow&7))<<3);
  const u16* srcP = Pb_ + srow*64 + sslot*8;
  const u16* srcK = Kb_ + srow*64 + sslot*8;
  const u16* srcV = Vt_ + srow*1024 + sslot*8;

  // ---- P tile 0/1 prefetch first (latency hides under Qv preloads)
  s16x8 p0 = *(const s16x8*)(srcP);
  s16x8 p1 = *(const s16x8*)(srcP + 4096);

  // ---- preload Qv fragments: primary band (w>>2), overlap band rows 17..32
  const int priBand = w>>2, jtp = w&3;
  s16x8 qvp[2], qvb2[2];
#pragma unroll
  for (int kk=0;kk<2;kk++){
    qvp[kk]  = *(const s16x8*)(Qv_ + (q0 + priBand*16 + l15)*64 + (kk*4+lg)*8);
    int r2 = q0 + 17 + l15; if (r2 > 1023) r2 = 1023;   // q0=992 edge: row32 unused
    qvb2[kk] = *(const s16x8*)(Qv_ + r2*64 + (kk*4+lg)*8);
  }

  // ---- phase 1: raw PS rows 0..32 -> sc (swzA)
  {
#pragma unroll
    for (int u=0; u<16; ++u){
      __syncthreads();
      *(s16x8*)tsw = p0;
      p0 = p1;
      if (u+2<16) p1 = *(const s16x8*)(srcP + (u+2)*4096);
      __syncthreads();
      {
        f32x4 ps = {0.f,0.f,0.f,0.f};
#pragma unroll
        for (int kk=0;kk<2;kk++){
          s16x8 pf = frag64(Ts, jtp*16 + l15, kk*4+lg);
          ps = MF(pf, qvp[kk], ps);           // PS[q=priBand*16+l15][j=jtp*16+lg*4+r]
        }
        const int prow = priBand*16 + l15;
        const int j0 = u*64 + jtp*16 + lg*4;
        s16x4 o;
#pragma unroll
        for (int r=0;r<4;r++) o[r] = (short)f2bf(ps[r]);
        *(s16x4*)(sc + prow*1024 + ((((j0>>2) ^ ((prow&15)<<1)))<<2)) = o;
      }
      if ((u&1) == (w>>2)){                   // overlap band rows 17..32, keep row 32
        f32x4 ps = {0.f,0.f,0.f,0.f};
#pragma unroll
        for (int kk=0;kk<2;kk++){
          s16x8 pf = frag64(Ts, (w&3)*16 + l15, kk*4+lg);
          ps = MF(pf, qvb2[kk], ps);
        }
        if (l15 == 15){
          const int j0 = u*64 + (w&3)*16 + lg*4;
          s16x4 o;
#pragma unroll
          for (int r=0;r<4;r++) o[r] = (short)f2bf(ps[r]);
          *(s16x4*)(sc + 32*1024 + ((j0>>2)<<2)) = o;   // row32: (row&15)=0, no xor
        }
      }
    }
  }

  __syncthreads();

  // ---- hoisted: Qu fragments + K tile 0/1 prefetch (hide under gather VALU)
  s16x8 qfu[2];
#pragma unroll
  for (int kk=0;kk<2;kk++)
    qfu[kk] = *(const s16x8*)(Qu_ + q*64 + (kk*4+lg)*8);
  s16x8 k0r = *(const s16x8*)(srcK);
  s16x8 k1r = *(const s16x8*)(srcK + 4096);

  // ---- gather pre-pass: stash rel-shifted pos for this thread's 64 phase-2 cells
  u32 stash[32];
#pragma unroll
  for (int kt=0; kt<16; ++kt){
#pragma unroll
    for (int rp=0; rp<2; ++rp){
      u32 wv = 0;
#pragma unroll
      for (int hh=0; hh<2; ++hh){
        const int k = kt*64 + sub*16 + lg*4 + rp*2 + hh;
        const int above = (k > q) ? 1 : 0;
        int jj = above ? (k - q - 2) : (1023 - q + k);
        const bool zero = (k == q+1);
        if (jj < 0) jj = 0;
        const int row = qi + above;
        const int addr = row*1024 + ((((jj>>2) ^ ((row&15)<<1)))<<2) + (jj&3);
        u32 v = zero ? 0u : (u32)sc[addr];
        wv |= v << (16*hh);
      }
      stash[kt*2+rp] = wv;
    }
  }

  // ---- phase 2: content Qu.K^T + stash -> sc (swzB); track f32 running max
  float rmax = -1e30f;
  {
#pragma unroll
    for (int kt=0; kt<16; ++kt){
      __syncthreads();                        // also separates gather from overwrite
      *(s16x8*)tsw = k0r;
      k0r = k1r;
      if (kt+2<16) k1r = *(const s16x8*)(srcK + (kt+2)*4096);
      __syncthreads();
      f32x4 a = {0.f,0.f,0.f,0.f};
#pragma unroll
      for (int kk=0;kk<2;kk++){
        s16x8 kf = frag64(Ts, sub*16 + l15, kk*4+lg);
        a = MF(kf, qfu[kk], a);               // D[k][q]
      }
      const int kb2 = kt*64 + sub*16 + lg*4;
      const u32 w0 = stash[kt*2], w1 = stash[kt*2+1];
      const float v0 = a[0] + bitsf(w0<<16);
      const float v1 = a[1] + bitsf(w0 & 0xffff0000u);
      const float v2 = a[2] + bitsf(w1<<16);
      const float v3 = a[3] + bitsf(w1 & 0xffff0000u);
      rmax = fmaxf(rmax, fmaxf(fmaxf(v0,v1), fmaxf(v2,v3)));
      s16x4 o;
      o[0]=(short)f2bf(v0); o[1]=(short)f2bf(v1);
      o[2]=(short)f2bf(v2); o[3]=(short)f2bf(v3);
      *(s16x4*)(sc + qi*1024 + SC_SLOT(qi, kb2>>3)*8 + (kb2&4)) = o;
    }
  }
  pmax[qi*16 + sub*4 + lg] = rmax;

  __syncthreads();

  // ---- hoisted: V tile 0/1 prefetch (hide under softmax VALU)
  s16x8 v0r = *(const s16x8*)(srcV);
  s16x8 v1r = *(const s16x8*)(srcV + 64);

  // ---- softmax: single exp+sum sweep; max from pmax partials
  {
    const int row = t>>4, c = t&15;
    float mx = pmax[row*16 + c];
    mx = fmaxf(mx, __shfl_xor(mx,1));
    mx = fmaxf(mx, __shfl_xor(mx,2));
    mx = fmaxf(mx, __shfl_xor(mx,4));
    mx = fmaxf(mx, __shfl_xor(mx,8));
    const float S2 = 0.063762029f;            // (1/sqrt(512)) * log2(e)
    const float nm = -mx * S2;
    float sum = 0.f;
#pragma unroll
    for (int i=0;i<8;i++){
      const int slot = c + 16*i;
      u16* p = sc + row*1024 + SC_SLOT(row,slot)*8;
      s16x8 v = *(const s16x8*)p;
      s16x8 o;
#pragma unroll
      for (int j2=0;j2<8;j2++){
        float e = exp2f(__builtin_fmaf(bf2f((u16)v[j2]), S2, nm));
        sum += e; o[j2] = (short)f2bf(e);
      }
      *(s16x8*)p = o;
    }
    sum += __shfl_xor(sum,1); sum += __shfl_xor(sum,2);
    sum += __shfl_xor(sum,4); sum += __shfl_xor(sum,8);
    if (c==0) stats[row] = 1.0f/sum;
  }

  // ---- PV: D[d][q] = sum_k V^T[d][k] P^T[k][q]
  f32x4 accC = {0.f,0.f,0.f,0.f};
  const int dtile = w>>1;
  {
#pragma unroll
    for (int kt=0; kt<16; ++kt){
      __syncthreads();
      *(s16x8*)tsw = v0r;
      v0r = v1r;
      if (kt+2<16) v1r = *(const s16x8*)(srcV + (kt+2)*64);
      __syncthreads();
#pragma unroll
      for (int kk=0;kk<2;kk++){
        const int slotk = kk*4 + lg;
        s16x8 vf = frag64(Ts, dtile*16 + l15, slotk);
        const int slot = kt*8 + slotk;
        s16x8 pfr = *(const s16x8*)(sc + qi*1024 + SC_SLOT(qi,slot)*8);
        accC = MF(vf, pfr, accC);
      }
    }
  }
  {
    const float inv = stats[qi];
    const int d0 = dtile*16 + lg*4;
    s16x4 o;
#pragma unroll
    for (int r=0;r<4;r++) o[r] = (short)f2bf(accC[r]*inv);
    *(s16x4*)(Ctx_ + (q0+qi)*64 + d0) = o;
  }
}

// ---------------- output projection ----------------
__global__ __launch_bounds__(256,2) void k_out(
  const u16* __restrict__ Ctx, const u16* __restrict__ WT,
  const float* __restrict__ bo, float* __restrict__ Out)
{
  const u16* W = WT + 4*262144;
  const int m0 = blockIdx.y*128, n0 = blockIdx.x*128;
  const int b = m0>>10, s0 = m0&1023;
  __shared__ u16 As[128*64];
  __shared__ u16 Bs[128*64];
  const int t = threadIdx.x, lane = t&63, w = t>>6;
  const int wm = w&1, wn = w>>1;
  f32x4 acc[4][4];
#pragma unroll
  for (int i=0;i<4;i++)
#pragma unroll
    for (int j=0;j<4;j++) acc[i][j] = (f32x4){0.f,0.f,0.f,0.f};

  for (int kt=0; kt<8; ++kt){
    const int k0 = kt*64, hh = kt;
    __syncthreads();
#pragma unroll
    for (int i=0;i<4;i++){
      int id = t + 256*i; int row = id>>3, slot = id&7;
      s16x8 v = *(const s16x8*)(Ctx + ((b*8+hh)*1024 + s0 + row)*64 + slot*8);
      *(s16x8*)(As + row*64 + ((slot^(row&7))<<3)) = v;
    }
#pragma unroll
    for (int i=0;i<4;i++){
      int id = t + 256*i; int row = id>>3, slot = id&7;
      s16x8 v = *(const s16x8*)(W + (n0+row)*512 + k0 + slot*8);
      *(s16x8*)(Bs + row*64 + ((slot^(row&7))<<3)) = v;
    }
    __syncthreads();
#pragma unroll
    for (int kk=0;kk<2;kk++){
      const int slotk = kk*4 + (lane>>4);
      s16x8 xf[4], wf[4];
#pragma unroll
      for (int j=0;j<4;j++){ int r = wm*64 + j*16 + (lane&15); xf[j] = frag64(As, r, slotk); }
#pragma unroll
      for (int i=0;i<4;i++){ int r = wn*64 + i*16 + (lane&15); wf[i] = frag64(Bs, r, slotk); }
#pragma unroll
      for (int i=0;i<4;i++)
#pragma unroll
        for (int j=0;j<4;j++) acc[i][j] = MF(wf[i], xf[j], acc[i][j]);
    }
  }
#pragma unroll
  for (int i=0;i<4;i++){
    const int n = n0 + wn*64 + i*16 + ((lane>>4)<<2);
    f32x4 bo4 = *(const f32x4*)(bo + n);
#pragma unroll
    for (int j=0;j<4;j++){
      const int m = m0 + wm*64 + j*16 + (lane&15);
      f32x4 o = acc[i][j] + bo4;
      *(f32x4*)(Out + m*512 + n) = o;
    }
  }
}

extern "C" void kernel_launch(void* const* d_in, const int* in_sizes, int n_in,
                              void* d_out, int out_size, void* d_ws, size_t ws_size,
                              hipStream_t stream)
{
  const float* query = (const float*)d_in[0];
  const float* key   = (const float*)d_in[1];
  const float* value = (const float*)d_in[2];
  const float* pos   = (const float*)d_in[3];
  const float* Wq = (const float*)d_in[4];
  const float* bq = (const float*)d_in[5];
  const float* Wk = (const float*)d_in[6];
  const float* bk = (const float*)d_in[7];
  const float* Wv = (const float*)d_in[8];
  const float* bv = (const float*)d_in[9];
  const float* Wp = (const float*)d_in[10];
  const float* Wo = (const float*)d_in[11];
  const float* bo = (const float*)d_in[12];
  const float* ub = (const float*)d_in[13];
  const float* vb = (const float*)d_in[14];
  float* Out = (float*)d_out;

  u16* ws  = (u16*)d_ws;
  u16* WT  = ws;                       // 5 * 262144
  u16* Qu  = ws + 1310720;             // each tensor: 8*8*1024*64 = 4194304
  u16* Qv  = Qu + 4194304;
  u16* Kb  = Qv + 4194304;
  u16* Pb  = Kb + 4194304;
  u16* Vt  = Pb + 4194304;
  u16* Ctx = Vt + 4194304;

  k_prep<<<dim3(320),  dim3(256), 0, stream>>>(Wq,Wk,Wv,Wp,Wo,WT);
  k_proj<<<dim3(1024), dim3(256), 0, stream>>>(query,key,value,pos,WT,bq,bk,bv,ub,vb,Qu,Qv,Kb,Pb,Vt);
  k_attn<<<dim3(2048), dim3(512), 0, stream>>>(Qu,Qv,Kb,Pb,Vt,Ctx);
  k_out<<<dim3(4,64),  dim3(256), 0, stream>>>(Ctx,WT,bo,Out);
}